// Round 4
// baseline (641.099 us; speedup 1.0000x reference)
//
#include <hip/hip_runtime.h>
#include <hip/hip_bf16.h>
#include <cstdint>
#include <cstddef>

#define S_LEN 2048
#define DM 1024
#define NEGV -1.0e9f

typedef __attribute__((ext_vector_type(8))) short bf16x8;
typedef __attribute__((ext_vector_type(4))) float f32x4;
typedef __attribute__((ext_vector_type(4))) unsigned short us4;
typedef __attribute__((ext_vector_type(4))) int i32x4;

__device__ __forceinline__ unsigned short f2bf(float f) {
  unsigned int u = __float_as_uint(f);
  unsigned int r = (u + 0x7fffu + ((u >> 16) & 1u)) >> 16;
  return (unsigned short)r;
}

__device__ __forceinline__ unsigned int pack_bf2(float a, float b) {
  return (unsigned int)f2bf(a) | ((unsigned int)f2bf(b) << 16);
}

__device__ __forceinline__ void async_copy16(const void* g, void* l) {
  __builtin_amdgcn_global_load_lds((const __attribute__((address_space(1))) void*)g,
                                   (__attribute__((address_space(3))) void*)l, 16, 0, 0);
}

// ---------------- f32 -> bf16 convert ----------------
__global__ void cvt_kernel(const float* __restrict__ src, unsigned short* __restrict__ dst, int n4) {
  int i = blockIdx.x * blockDim.x + threadIdx.x;
  if (i >= n4) return;
  const float4 v = reinterpret_cast<const float4*>(src)[i];
  us4 o;
  o[0] = f2bf(v.x); o[1] = f2bf(v.y); o[2] = f2bf(v.z); o[3] = f2bf(v.w);
  reinterpret_cast<us4*>(dst)[i] = o;
}

// ---------------- projection GEMM (unchanged, passed) ----------------
__global__ __launch_bounds__(256) void proj_gemm(
    const unsigned short* __restrict__ Xq, const unsigned short* __restrict__ Wqw,
    const float* __restrict__ bq, unsigned short* __restrict__ Cq,
    const unsigned short* __restrict__ Xk, const unsigned short* __restrict__ Wkw,
    const float* __restrict__ bk, unsigned short* __restrict__ Ck,
    const unsigned short* __restrict__ Xv, const unsigned short* __restrict__ Wvw,
    const float* __restrict__ bv, unsigned short* __restrict__ Cv) {
  const unsigned short* X; const unsigned short* W; const float* bias; unsigned short* C;
  if (blockIdx.z == 0)      { X = Xq; W = Wqw; bias = bq; C = Cq; }
  else if (blockIdx.z == 1) { X = Xk; W = Wkw; bias = bk; C = Ck; }
  else                      { X = Xv; W = Wvw; bias = bv; C = Cv; }

  __shared__ unsigned short Ab[128 * 64];
  __shared__ unsigned short Bb[128 * 64];

  const int t  = threadIdx.x;
  const int wv = t >> 6, l = t & 63;
  const int lr = l & 15, lg = l >> 4;
  const int wr = wv >> 1, wc = wv & 1;
  const int m0 = blockIdx.y * 128, n0 = blockIdx.x * 128;

  const f32x4 fz = {0.f, 0.f, 0.f, 0.f};
  f32x4 acc[4][4];
#pragma unroll
  for (int m = 0; m < 4; ++m)
#pragma unroll
    for (int n = 0; n < 4; ++n) acc[m][n] = fz;

  const int srow = t >> 3;
  const int sc16 = t & 7;

  for (int kt = 0; kt < 16; ++kt) {
    const int kb = kt * 64;
#pragma unroll
    for (int it = 0; it < 4; ++it) {
      const int row = it * 32 + srow;
      const int c16 = sc16 ^ (row & 7);
      const unsigned short* gA = X + (size_t)(m0 + row) * DM + kb + c16 * 8;
      const unsigned short* gB = W + (size_t)(n0 + row) * DM + kb + c16 * 8;
      async_copy16(gA, (char*)Ab + it * 4096 + wv * 1024);
      async_copy16(gB, (char*)Bb + it * 4096 + wv * 1024);
    }
    __syncthreads();
#pragma unroll
    for (int kk = 0; kk < 2; ++kk) {
      bf16x8 af[4], bfr[4];
      const int c16 = kk * 4 + lg;
      const int sw = (c16 ^ (lr & 7)) * 16;
#pragma unroll
      for (int m = 0; m < 4; ++m) {
        const int row = wr * 64 + m * 16 + lr;
        af[m] = *(const bf16x8*)((const char*)Ab + row * 128 + sw);
      }
#pragma unroll
      for (int n = 0; n < 4; ++n) {
        const int row = wc * 64 + n * 16 + lr;
        bfr[n] = *(const bf16x8*)((const char*)Bb + row * 128 + sw);
      }
#pragma unroll
      for (int m = 0; m < 4; ++m)
#pragma unroll
        for (int n = 0; n < 4; ++n)
          acc[m][n] = __builtin_amdgcn_mfma_f32_16x16x32_bf16(af[m], bfr[n], acc[m][n], 0, 0, 0);
    }
    __syncthreads();
  }

#pragma unroll
  for (int n = 0; n < 4; ++n) {
    const int ccol = n0 + wc * 64 + n * 16 + lr;
    const float bb = bias[ccol];
#pragma unroll
    for (int m = 0; m < 4; ++m) {
      const int crow0 = m0 + wr * 64 + m * 16 + lg * 4;
#pragma unroll
      for (int j = 0; j < 4; ++j)
        C[(size_t)(crow0 + j) * DM + ccol] = f2bf(acc[m][n][j] + bb);
    }
  }
}

// ---------------- V transpose: [4096,1024] -> [1024,4096] ----------------
__global__ void transpose_bf(const unsigned short* __restrict__ src, unsigned short* __restrict__ dst) {
  __shared__ unsigned short tb[32][33];
  const int x = threadIdx.x & 31, y = threadIdx.x >> 5;
  const int bx = blockIdx.x, by = blockIdx.y;
#pragma unroll
  for (int r = 0; r < 32; r += 8)
    tb[r + y][x] = src[(size_t)(by * 32 + r + y) * DM + bx * 32 + x];
  __syncthreads();
#pragma unroll
  for (int r = 0; r < 32; r += 8)
    dst[(size_t)(bx * 32 + r + y) * 4096 + by * 32 + x] = tb[x][r + y];
}

// ---------------- fused attention v3: single-pass, P in registers ----------------
// Block = 256 threads (4 waves) = one (b,h,16q) tile; wave w owns keys [w*512,(w+1)*512).
// QK^T+mask+exp once; unnormalized exp kept packed bf16 in 64 VGPRs; block-reduce
// row sums (2 barriers total); then normalize + float4 attn stores + PV MFMA.
__global__ __launch_bounds__(256, 4) void attn3_kernel(
    const unsigned short* __restrict__ Qp, const unsigned short* __restrict__ Kp,
    const unsigned short* __restrict__ Vt, const int* __restrict__ mask,
    float* __restrict__ outp, float* __restrict__ attnp) {
  __shared__ float rsred[4][16];
  __shared__ float outred[4][16 * 64];               // 16 KB
  __shared__ unsigned short Pb[4][2][16 * 40];       // 10 KB, double-buffered repack

  const int bx = blockIdx.x;
  // qt fastest (same (b,h) K/V head stays hot in one XCD's L2), bijective XCD swizzle
  const int t = ((bx & 7) << 9) | (bx >> 3);
  const int qt = t & 127;
  const int h  = (t >> 7) & 15;
  const int b  = t >> 11;
  const int q0 = qt << 4;

  const int w = threadIdx.x >> 6, l = threadIdx.x & 63;
  const int lr = l & 15, lg = l >> 4;
  const int kw0 = w << 9;

  const float scale = 0.125f;
  const f32x4 fz = {0.f, 0.f, 0.f, 0.f};

  // Q as B-operand: lane holds Q[q0+lr][lg*8..+7]
  const unsigned short* Qh = Qp + (size_t)(b * S_LEN + q0 + lr) * DM + h * 64;
  const bf16x8 qf0 = *(const bf16x8*)(Qh + lg * 8);
  const bf16x8 qf1 = *(const bf16x8*)(Qh + 32 + lg * 8);

  const unsigned short* Kh = Kp + (size_t)b * S_LEN * DM + h * 64;
  const int* mrow = mask + (size_t)(b * S_LEN + q0 + lr) * S_LEN + kw0;

  // ---- QK^T + mask + exp, packed bf16 in regs; row-sum accumulate ----
  unsigned int pk[32][2];
  float rs = 0.f;
#pragma unroll
  for (int i = 0; i < 32; ++i) {
    const int kc = kw0 + i * 16;
    const unsigned short* Kr = Kh + (size_t)(kc + lr) * DM;
    const bf16x8 ka0 = *(const bf16x8*)(Kr + lg * 8);
    const bf16x8 ka1 = *(const bf16x8*)(Kr + 32 + lg * 8);
    const i32x4 m4 = *(const i32x4*)(mrow + i * 16 + lg * 4);
    f32x4 sc = fz;
    sc = __builtin_amdgcn_mfma_f32_16x16x32_bf16(ka0, qf0, sc, 0, 0, 0);
    sc = __builtin_amdgcn_mfma_f32_16x16x32_bf16(ka1, qf1, sc, 0, 0, 0);
    const float e0 = __expf((m4[0] == 0) ? NEGV : sc[0] * scale);
    const float e1 = __expf((m4[1] == 0) ? NEGV : sc[1] * scale);
    const float e2 = __expf((m4[2] == 0) ? NEGV : sc[2] * scale);
    const float e3 = __expf((m4[3] == 0) ? NEGV : sc[3] * scale);
    rs += (e0 + e1) + (e2 + e3);
    pk[i][0] = pack_bf2(e0, e1);
    pk[i][1] = pack_bf2(e2, e3);
  }
  // per-wave row sum for q=lr (4 lanes with same lr hold partial sums)
  rs += __shfl_xor(rs, 16, 64);
  rs += __shfl_xor(rs, 32, 64);
  if (l < 16) rsred[w][l] = rs;
  __syncthreads();
  const float rinv = 1.0f / (rsred[0][lr] + rsred[1][lr] + rsred[2][lr] + rsred[3][lr]);

  // ---- normalize + attn store + PV ----
  float* attnq = attnp + (size_t)((b * 16 + h) * S_LEN + q0 + lr) * S_LEN + kw0;
  const unsigned short* Vh = Vt + (size_t)(h * 64) * (2 * S_LEN) + (size_t)b * S_LEN + kw0;

  f32x4 oacc[4];
#pragma unroll
  for (int n = 0; n < 4; ++n) oacc[n] = fz;

#pragma unroll
  for (int win = 0; win < 16; ++win) {
    const int wb = win * 32;
    const unsigned int a0 = pk[2 * win][0],     a1 = pk[2 * win][1];
    const unsigned int b0 = pk[2 * win + 1][0], b1 = pk[2 * win + 1][1];
    float p0 = __uint_as_float(a0 << 16) * rinv;
    float p1 = __uint_as_float(a0 & 0xffff0000u) * rinv;
    float p2 = __uint_as_float(a1 << 16) * rinv;
    float p3 = __uint_as_float(a1 & 0xffff0000u) * rinv;
    float p4 = __uint_as_float(b0 << 16) * rinv;
    float p5 = __uint_as_float(b0 & 0xffff0000u) * rinv;
    float p6 = __uint_as_float(b1 << 16) * rinv;
    float p7 = __uint_as_float(b1 & 0xffff0000u) * rinv;
    const float4 st0 = {p0, p1, p2, p3};
    const float4 st1 = {p4, p5, p6, p7};
    *(float4*)(attnq + wb + lg * 4) = st0;          // 64B/row per instr, coalesced
    *(float4*)(attnq + wb + 16 + lg * 4) = st1;

    us4 w0, w1;
    w0[0] = f2bf(p0); w0[1] = f2bf(p1); w0[2] = f2bf(p2); w0[3] = f2bf(p3);
    w1[0] = f2bf(p4); w1[1] = f2bf(p5); w1[2] = f2bf(p6); w1[3] = f2bf(p7);
    unsigned short* pb = &Pb[w][win & 1][0];
    *(us4*)(pb + lr * 40 + lg * 4) = w0;
    *(us4*)(pb + lr * 40 + 16 + lg * 4) = w1;
    const bf16x8 pa = *(const bf16x8*)(pb + lr * 40 + lg * 8);  // A[q=lr][k=lg*8..+7]

#pragma unroll
    for (int n = 0; n < 4; ++n) {
      const bf16x8 vb = *(const bf16x8*)(Vh + (size_t)(n * 16 + lr) * (2 * S_LEN) + wb + lg * 8);
      oacc[n] = __builtin_amdgcn_mfma_f32_16x16x32_bf16(pa, vb, oacc[n], 0, 0, 0);
    }
  }

  // ---- cross-wave out reduction ----
#pragma unroll
  for (int n = 0; n < 4; ++n)
#pragma unroll
    for (int j = 0; j < 4; ++j)
      outred[w][(lg * 4 + j) * 64 + n * 16 + lr] = oacc[n][j];
  __syncthreads();
  {
    const int q = threadIdx.x >> 4;
    const int d0 = (threadIdx.x & 15) * 4;
    const f32x4 s0 = *(const f32x4*)&outred[0][q * 64 + d0];
    const f32x4 s1 = *(const f32x4*)&outred[1][q * 64 + d0];
    const f32x4 s2 = *(const f32x4*)&outred[2][q * 64 + d0];
    const f32x4 s3 = *(const f32x4*)&outred[3][q * 64 + d0];
    float4 o;
    o.x = (s0[0] + s1[0]) + (s2[0] + s3[0]);
    o.y = (s0[1] + s1[1]) + (s2[1] + s3[1]);
    o.z = (s0[2] + s1[2]) + (s2[2] + s3[2]);
    o.w = (s0[3] + s1[3]) + (s2[3] + s3[3]);
    *(float4*)(outp + (size_t)(b * S_LEN + q0 + q) * DM + h * 64 + d0) = o;
  }
}

extern "C" void kernel_launch(void* const* d_in, const int* in_sizes, int n_in,
                              void* d_out, int out_size, void* d_ws, size_t ws_size,
                              hipStream_t stream) {
  const float* query = (const float*)d_in[0];
  const float* key_  = (const float*)d_in[1];
  const float* value = (const float*)d_in[2];
  const int*   mask  = (const int*)d_in[3];
  const float* Wq = (const float*)d_in[4];
  const float* bq = (const float*)d_in[5];
  const float* Wk = (const float*)d_in[6];
  const float* bk = (const float*)d_in[7];
  const float* Wv = (const float*)d_in[8];
  const float* bv = (const float*)d_in[9];

  float* outp  = (float*)d_out;
  float* attnp = outp + (size_t)2 * S_LEN * DM;

  unsigned short* ws  = (unsigned short*)d_ws;
  unsigned short* qbf = ws;
  unsigned short* kbf = qbf + 4194304;
  unsigned short* vbf = kbf + 4194304;
  unsigned short* wqb = vbf + 4194304;
  unsigned short* wkb = wqb + 1048576;
  unsigned short* wvb = wkb + 1048576;
  unsigned short* qp  = wvb + 1048576;
  unsigned short* kp  = qp + 4194304;
  unsigned short* vp  = kp + 4194304;
  unsigned short* vt  = vp + 4194304;

  cvt_kernel<<<4096, 256, 0, stream>>>(query, qbf, 1048576);
  cvt_kernel<<<4096, 256, 0, stream>>>(key_,  kbf, 1048576);
  cvt_kernel<<<4096, 256, 0, stream>>>(value, vbf, 1048576);
  cvt_kernel<<<1024, 256, 0, stream>>>(Wq, wqb, 262144);
  cvt_kernel<<<1024, 256, 0, stream>>>(Wk, wkb, 262144);
  cvt_kernel<<<1024, 256, 0, stream>>>(Wv, wvb, 262144);

  proj_gemm<<<dim3(8, 32, 3), 256, 0, stream>>>(qbf, wqb, bq, qp,
                                                kbf, wkb, bk, kp,
                                                vbf, wvb, bv, vp);
  transpose_bf<<<dim3(32, 128), 256, 0, stream>>>(vp, vt);
  attn3_kernel<<<4096, 256, 0, stream>>>(qp, kp, vt, mask, outp, attnp);
}

// Round 5
// 479.224 us; speedup vs baseline: 1.3378x; 1.3378x over previous
//
#include <hip/hip_runtime.h>
#include <hip/hip_bf16.h>
#include <cstdint>
#include <cstddef>

#define S_LEN 2048
#define DM 1024
#define NEGV -1.0e9f

typedef __attribute__((ext_vector_type(8))) short bf16x8;
typedef __attribute__((ext_vector_type(4))) float f32x4;
typedef __attribute__((ext_vector_type(4))) unsigned short us4;
typedef __attribute__((ext_vector_type(4))) int i32x4;

__device__ __forceinline__ unsigned short f2bf(float f) {
  unsigned int u = __float_as_uint(f);
  unsigned int r = (u + 0x7fffu + ((u >> 16) & 1u)) >> 16;
  return (unsigned short)r;
}

__device__ __forceinline__ unsigned int pack_bf2(float a, float b) {
  return (unsigned int)f2bf(a) | ((unsigned int)f2bf(b) << 16);
}

__device__ __forceinline__ void async_copy16(const void* g, void* l) {
  __builtin_amdgcn_global_load_lds((const __attribute__((address_space(1))) void*)g,
                                   (__attribute__((address_space(3))) void*)l, 16, 0, 0);
}

// ---------------- f32 -> bf16 convert ----------------
__global__ void cvt_kernel(const float* __restrict__ src, unsigned short* __restrict__ dst, int n4) {
  int i = blockIdx.x * blockDim.x + threadIdx.x;
  if (i >= n4) return;
  const float4 v = reinterpret_cast<const float4*>(src)[i];
  us4 o;
  o[0] = f2bf(v.x); o[1] = f2bf(v.y); o[2] = f2bf(v.z); o[3] = f2bf(v.w);
  reinterpret_cast<us4*>(dst)[i] = o;
}

// ---------------- projection GEMM (unchanged, passed) ----------------
__global__ __launch_bounds__(256) void proj_gemm(
    const unsigned short* __restrict__ Xq, const unsigned short* __restrict__ Wqw,
    const float* __restrict__ bq, unsigned short* __restrict__ Cq,
    const unsigned short* __restrict__ Xk, const unsigned short* __restrict__ Wkw,
    const float* __restrict__ bk, unsigned short* __restrict__ Ck,
    const unsigned short* __restrict__ Xv, const unsigned short* __restrict__ Wvw,
    const float* __restrict__ bv, unsigned short* __restrict__ Cv) {
  const unsigned short* X; const unsigned short* W; const float* bias; unsigned short* C;
  if (blockIdx.z == 0)      { X = Xq; W = Wqw; bias = bq; C = Cq; }
  else if (blockIdx.z == 1) { X = Xk; W = Wkw; bias = bk; C = Ck; }
  else                      { X = Xv; W = Wvw; bias = bv; C = Cv; }

  __shared__ unsigned short Ab[128 * 64];
  __shared__ unsigned short Bb[128 * 64];

  const int t  = threadIdx.x;
  const int wv = t >> 6, l = t & 63;
  const int lr = l & 15, lg = l >> 4;
  const int wr = wv >> 1, wc = wv & 1;
  const int m0 = blockIdx.y * 128, n0 = blockIdx.x * 128;

  const f32x4 fz = {0.f, 0.f, 0.f, 0.f};
  f32x4 acc[4][4];
#pragma unroll
  for (int m = 0; m < 4; ++m)
#pragma unroll
    for (int n = 0; n < 4; ++n) acc[m][n] = fz;

  const int srow = t >> 3;
  const int sc16 = t & 7;

  for (int kt = 0; kt < 16; ++kt) {
    const int kb = kt * 64;
#pragma unroll
    for (int it = 0; it < 4; ++it) {
      const int row = it * 32 + srow;
      const int c16 = sc16 ^ (row & 7);
      const unsigned short* gA = X + (size_t)(m0 + row) * DM + kb + c16 * 8;
      const unsigned short* gB = W + (size_t)(n0 + row) * DM + kb + c16 * 8;
      async_copy16(gA, (char*)Ab + it * 4096 + wv * 1024);
      async_copy16(gB, (char*)Bb + it * 4096 + wv * 1024);
    }
    __syncthreads();
#pragma unroll
    for (int kk = 0; kk < 2; ++kk) {
      bf16x8 af[4], bfr[4];
      const int c16 = kk * 4 + lg;
      const int sw = (c16 ^ (lr & 7)) * 16;
#pragma unroll
      for (int m = 0; m < 4; ++m) {
        const int row = wr * 64 + m * 16 + lr;
        af[m] = *(const bf16x8*)((const char*)Ab + row * 128 + sw);
      }
#pragma unroll
      for (int n = 0; n < 4; ++n) {
        const int row = wc * 64 + n * 16 + lr;
        bfr[n] = *(const bf16x8*)((const char*)Bb + row * 128 + sw);
      }
#pragma unroll
      for (int m = 0; m < 4; ++m)
#pragma unroll
        for (int n = 0; n < 4; ++n)
          acc[m][n] = __builtin_amdgcn_mfma_f32_16x16x32_bf16(af[m], bfr[n], acc[m][n], 0, 0, 0);
    }
    __syncthreads();
  }

#pragma unroll
  for (int n = 0; n < 4; ++n) {
    const int ccol = n0 + wc * 64 + n * 16 + lr;
    const float bb = bias[ccol];
#pragma unroll
    for (int m = 0; m < 4; ++m) {
      const int crow0 = m0 + wr * 64 + m * 16 + lg * 4;
#pragma unroll
      for (int j = 0; j < 4; ++j)
        C[(size_t)(crow0 + j) * DM + ccol] = f2bf(acc[m][n][j] + bb);
    }
  }
}

// ---------------- V transpose: [4096,1024] -> [1024,4096] ----------------
__global__ void transpose_bf(const unsigned short* __restrict__ src, unsigned short* __restrict__ dst) {
  __shared__ unsigned short tb[32][33];
  const int x = threadIdx.x & 31, y = threadIdx.x >> 5;
  const int bx = blockIdx.x, by = blockIdx.y;
#pragma unroll
  for (int r = 0; r < 32; r += 8)
    tb[r + y][x] = src[(size_t)(by * 32 + r + y) * DM + bx * 32 + x];
  __syncthreads();
#pragma unroll
  for (int r = 0; r < 32; r += 8)
    dst[(size_t)(bx * 32 + r + y) * 4096 + by * 32 + x] = tb[x][r + y];
}

// ---------------- fused attention v4: single-pass, P in regs, 8 waves/block ----------------
// Block = 512 threads (8 waves) = one (b,h,16q) tile; wave w owns keys [w*256,(w+1)*256)
// -> pk is only 32 VGPRs/lane (v3's 64 spilled to scratch). One K pass; unnormalized
// exp packed bf16 in regs; block row-sum reduce; normalize + float4 attn stores + PV.
__global__ __launch_bounds__(512, 4) void attn4_kernel(
    const unsigned short* __restrict__ Qp, const unsigned short* __restrict__ Kp,
    const unsigned short* __restrict__ Vt, const int* __restrict__ mask,
    float* __restrict__ outp, float* __restrict__ attnp) {
  __shared__ float rsred[8][16];
  __shared__ float outred[8][16 * 64];               // 32 KB
  __shared__ unsigned short Pb[8][2][16 * 40];       // 20 KB, double-buffered repack

  const int bx = blockIdx.x;
  const int t = ((bx & 7) << 9) | (bx >> 3);  // bijective XCD swizzle (4096 % 8 == 0)
  const int h  = t & 15;                       // h fastest: 16 heads share mask rows
  const int qt = (t >> 4) & 127;
  const int b  = t >> 11;
  const int q0 = qt << 4;

  const int w = threadIdx.x >> 6, l = threadIdx.x & 63;
  const int lr = l & 15, lg = l >> 4;
  const int kw0 = w << 8;                      // 256 keys per wave

  const float scale = 0.125f;
  const f32x4 fz = {0.f, 0.f, 0.f, 0.f};

  // Q as B-operand: lane holds Q[q0+lr][lg*8..+7]
  const unsigned short* Qh = Qp + (size_t)(b * S_LEN + q0 + lr) * DM + h * 64;
  const bf16x8 qf0 = *(const bf16x8*)(Qh + lg * 8);
  const bf16x8 qf1 = *(const bf16x8*)(Qh + 32 + lg * 8);

  const unsigned short* Kh = Kp + (size_t)b * S_LEN * DM + h * 64 + (size_t)kw0 * DM;
  const int* mrow = mask + (size_t)(b * S_LEN + q0 + lr) * S_LEN + kw0;

  // ---- QK^T + mask + exp (one pass over K), packed bf16 in regs ----
  unsigned int pkA[16], pkB[16];
  float rs = 0.f;
#pragma unroll
  for (int i = 0; i < 16; ++i) {
    const unsigned short* Kr = Kh + (size_t)(i * 16 + lr) * DM;
    const bf16x8 ka0 = *(const bf16x8*)(Kr + lg * 8);
    const bf16x8 ka1 = *(const bf16x8*)(Kr + 32 + lg * 8);
    const i32x4 m4 = *(const i32x4*)(mrow + i * 16 + lg * 4);
    f32x4 sc = fz;
    sc = __builtin_amdgcn_mfma_f32_16x16x32_bf16(ka0, qf0, sc, 0, 0, 0);
    sc = __builtin_amdgcn_mfma_f32_16x16x32_bf16(ka1, qf1, sc, 0, 0, 0);
    const float e0 = __expf((m4[0] == 0) ? NEGV : sc[0] * scale);
    const float e1 = __expf((m4[1] == 0) ? NEGV : sc[1] * scale);
    const float e2 = __expf((m4[2] == 0) ? NEGV : sc[2] * scale);
    const float e3 = __expf((m4[3] == 0) ? NEGV : sc[3] * scale);
    rs += (e0 + e1) + (e2 + e3);
    pkA[i] = pack_bf2(e0, e1);
    pkB[i] = pack_bf2(e2, e3);
  }
  // per-wave row sum for q=lr (4 lanes with same lr hold partials)
  rs += __shfl_xor(rs, 16, 64);
  rs += __shfl_xor(rs, 32, 64);
  if (l < 16) rsred[w][l] = rs;
  __syncthreads();
  float ssum = 0.f;
#pragma unroll
  for (int ww = 0; ww < 8; ++ww) ssum += rsred[ww][lr];
  const float rinv = 1.0f / ssum;

  // ---- normalize + attn store + PV ----
  float* attnq = attnp + (size_t)((b * 16 + h) * S_LEN + q0 + lr) * S_LEN + kw0;
  const unsigned short* Vh = Vt + (size_t)(h * 64) * (2 * S_LEN) + (size_t)b * S_LEN + kw0;

  f32x4 oacc[4];
#pragma unroll
  for (int n = 0; n < 4; ++n) oacc[n] = fz;

#pragma unroll
  for (int win = 0; win < 8; ++win) {
    const int wb = win * 32;
    const unsigned int a0 = pkA[2 * win],     a1 = pkB[2 * win];
    const unsigned int b0 = pkA[2 * win + 1], b1 = pkB[2 * win + 1];
    float p0 = __uint_as_float(a0 << 16) * rinv;
    float p1 = __uint_as_float(a0 & 0xffff0000u) * rinv;
    float p2 = __uint_as_float(a1 << 16) * rinv;
    float p3 = __uint_as_float(a1 & 0xffff0000u) * rinv;
    float p4 = __uint_as_float(b0 << 16) * rinv;
    float p5 = __uint_as_float(b0 & 0xffff0000u) * rinv;
    float p6 = __uint_as_float(b1 << 16) * rinv;
    float p7 = __uint_as_float(b1 & 0xffff0000u) * rinv;
    const float4 st0 = {p0, p1, p2, p3};
    const float4 st1 = {p4, p5, p6, p7};
    *(float4*)(attnq + wb + lg * 4) = st0;          // 64B segments, coalesced per lr-row
    *(float4*)(attnq + wb + 16 + lg * 4) = st1;

    us4 w0, w1;
    w0[0] = f2bf(p0); w0[1] = f2bf(p1); w0[2] = f2bf(p2); w0[3] = f2bf(p3);
    w1[0] = f2bf(p4); w1[1] = f2bf(p5); w1[2] = f2bf(p6); w1[3] = f2bf(p7);
    unsigned short* pb = &Pb[w][win & 1][0];
    *(us4*)(pb + lr * 40 + lg * 4) = w0;
    *(us4*)(pb + lr * 40 + 16 + lg * 4) = w1;
    const bf16x8 pa = *(const bf16x8*)(pb + lr * 40 + lg * 8);  // A[q=lr][k=lg*8..+7]

#pragma unroll
    for (int n = 0; n < 4; ++n) {
      const bf16x8 vb = *(const bf16x8*)(Vh + (size_t)(n * 16 + lr) * (2 * S_LEN) + wb + lg * 8);
      oacc[n] = __builtin_amdgcn_mfma_f32_16x16x32_bf16(pa, vb, oacc[n], 0, 0, 0);
    }
  }

  // ---- cross-wave out reduction (8 partials) ----
#pragma unroll
  for (int n = 0; n < 4; ++n)
#pragma unroll
    for (int j = 0; j < 4; ++j)
      outred[w][(lg * 4 + j) * 64 + n * 16 + lr] = oacc[n][j];
  __syncthreads();
  if (threadIdx.x < 256) {
    const int q = threadIdx.x >> 4;
    const int d0 = (threadIdx.x & 15) * 4;
    float4 o = {0.f, 0.f, 0.f, 0.f};
#pragma unroll
    for (int ww = 0; ww < 8; ++ww) {
      const f32x4 s = *(const f32x4*)&outred[ww][q * 64 + d0];
      o.x += s[0]; o.y += s[1]; o.z += s[2]; o.w += s[3];
    }
    *(float4*)(outp + (size_t)(b * S_LEN + q0 + q) * DM + h * 64 + d0) = o;
  }
}

extern "C" void kernel_launch(void* const* d_in, const int* in_sizes, int n_in,
                              void* d_out, int out_size, void* d_ws, size_t ws_size,
                              hipStream_t stream) {
  const float* query = (const float*)d_in[0];
  const float* key_  = (const float*)d_in[1];
  const float* value = (const float*)d_in[2];
  const int*   mask  = (const int*)d_in[3];
  const float* Wq = (const float*)d_in[4];
  const float* bq = (const float*)d_in[5];
  const float* Wk = (const float*)d_in[6];
  const float* bk = (const float*)d_in[7];
  const float* Wv = (const float*)d_in[8];
  const float* bv = (const float*)d_in[9];

  float* outp  = (float*)d_out;
  float* attnp = outp + (size_t)2 * S_LEN * DM;

  unsigned short* ws  = (unsigned short*)d_ws;
  unsigned short* qbf = ws;
  unsigned short* kbf = qbf + 4194304;
  unsigned short* vbf = kbf + 4194304;
  unsigned short* wqb = vbf + 4194304;
  unsigned short* wkb = wqb + 1048576;
  unsigned short* wvb = wkb + 1048576;
  unsigned short* qp  = wvb + 1048576;
  unsigned short* kp  = qp + 4194304;
  unsigned short* vp  = kp + 4194304;
  unsigned short* vt  = vp + 4194304;

  cvt_kernel<<<4096, 256, 0, stream>>>(query, qbf, 1048576);
  cvt_kernel<<<4096, 256, 0, stream>>>(key_,  kbf, 1048576);
  cvt_kernel<<<4096, 256, 0, stream>>>(value, vbf, 1048576);
  cvt_kernel<<<1024, 256, 0, stream>>>(Wq, wqb, 262144);
  cvt_kernel<<<1024, 256, 0, stream>>>(Wk, wkb, 262144);
  cvt_kernel<<<1024, 256, 0, stream>>>(Wv, wvb, 262144);

  proj_gemm<<<dim3(8, 32, 3), 256, 0, stream>>>(qbf, wqb, bq, qp,
                                                kbf, wkb, bk, kp,
                                                vbf, wvb, bv, vp);
  transpose_bf<<<dim3(32, 128), 256, 0, stream>>>(vp, vt);
  attn4_kernel<<<4096, 512, 0, stream>>>(qp, kp, vt, mask, outp, attnp);
}

// Round 6
// 431.437 us; speedup vs baseline: 1.4860x; 1.1108x over previous
//
#include <hip/hip_runtime.h>
#include <hip/hip_bf16.h>
#include <cstdint>
#include <cstddef>

#define S_LEN 2048
#define DM 1024
#define NEGV -1.0e9f

typedef __attribute__((ext_vector_type(8))) short bf16x8;
typedef __attribute__((ext_vector_type(4))) float f32x4;
typedef __attribute__((ext_vector_type(4))) unsigned short us4;
typedef __attribute__((ext_vector_type(4))) int i32x4;

__device__ __forceinline__ unsigned short f2bf(float f) {
  unsigned int u = __float_as_uint(f);
  unsigned int r = (u + 0x7fffu + ((u >> 16) & 1u)) >> 16;
  return (unsigned short)r;
}

__device__ __forceinline__ unsigned int pack_bf2(float a, float b) {
  return (unsigned int)f2bf(a) | ((unsigned int)f2bf(b) << 16);
}

__device__ __forceinline__ void async_copy16(const void* g, void* l) {
  __builtin_amdgcn_global_load_lds((const __attribute__((address_space(1))) void*)g,
                                   (__attribute__((address_space(3))) void*)l, 16, 0, 0);
}

// ---------------- f32 -> bf16 convert ----------------
__global__ void cvt_kernel(const float* __restrict__ src, unsigned short* __restrict__ dst, int n4) {
  int i = blockIdx.x * blockDim.x + threadIdx.x;
  if (i >= n4) return;
  const float4 v = reinterpret_cast<const float4*>(src)[i];
  us4 o;
  o[0] = f2bf(v.x); o[1] = f2bf(v.y); o[2] = f2bf(v.z); o[3] = f2bf(v.w);
  reinterpret_cast<us4*>(dst)[i] = o;
}

// ---------------- projection GEMM (unchanged, passed) ----------------
__global__ __launch_bounds__(256) void proj_gemm(
    const unsigned short* __restrict__ Xq, const unsigned short* __restrict__ Wqw,
    const float* __restrict__ bq, unsigned short* __restrict__ Cq,
    const unsigned short* __restrict__ Xk, const unsigned short* __restrict__ Wkw,
    const float* __restrict__ bk, unsigned short* __restrict__ Ck,
    const unsigned short* __restrict__ Xv, const unsigned short* __restrict__ Wvw,
    const float* __restrict__ bv, unsigned short* __restrict__ Cv) {
  const unsigned short* X; const unsigned short* W; const float* bias; unsigned short* C;
  if (blockIdx.z == 0)      { X = Xq; W = Wqw; bias = bq; C = Cq; }
  else if (blockIdx.z == 1) { X = Xk; W = Wkw; bias = bk; C = Ck; }
  else                      { X = Xv; W = Wvw; bias = bv; C = Cv; }

  __shared__ unsigned short Ab[128 * 64];
  __shared__ unsigned short Bb[128 * 64];

  const int t  = threadIdx.x;
  const int wv = t >> 6, l = t & 63;
  const int lr = l & 15, lg = l >> 4;
  const int wr = wv >> 1, wc = wv & 1;
  const int m0 = blockIdx.y * 128, n0 = blockIdx.x * 128;

  const f32x4 fz = {0.f, 0.f, 0.f, 0.f};
  f32x4 acc[4][4];
#pragma unroll
  for (int m = 0; m < 4; ++m)
#pragma unroll
    for (int n = 0; n < 4; ++n) acc[m][n] = fz;

  const int srow = t >> 3;
  const int sc16 = t & 7;

  for (int kt = 0; kt < 16; ++kt) {
    const int kb = kt * 64;
#pragma unroll
    for (int it = 0; it < 4; ++it) {
      const int row = it * 32 + srow;
      const int c16 = sc16 ^ (row & 7);
      const unsigned short* gA = X + (size_t)(m0 + row) * DM + kb + c16 * 8;
      const unsigned short* gB = W + (size_t)(n0 + row) * DM + kb + c16 * 8;
      async_copy16(gA, (char*)Ab + it * 4096 + wv * 1024);
      async_copy16(gB, (char*)Bb + it * 4096 + wv * 1024);
    }
    __syncthreads();
#pragma unroll
    for (int kk = 0; kk < 2; ++kk) {
      bf16x8 af[4], bfr[4];
      const int c16 = kk * 4 + lg;
      const int sw = (c16 ^ (lr & 7)) * 16;
#pragma unroll
      for (int m = 0; m < 4; ++m) {
        const int row = wr * 64 + m * 16 + lr;
        af[m] = *(const bf16x8*)((const char*)Ab + row * 128 + sw);
      }
#pragma unroll
      for (int n = 0; n < 4; ++n) {
        const int row = wc * 64 + n * 16 + lr;
        bfr[n] = *(const bf16x8*)((const char*)Bb + row * 128 + sw);
      }
#pragma unroll
      for (int m = 0; m < 4; ++m)
#pragma unroll
        for (int n = 0; n < 4; ++n)
          acc[m][n] = __builtin_amdgcn_mfma_f32_16x16x32_bf16(af[m], bfr[n], acc[m][n], 0, 0, 0);
    }
    __syncthreads();
  }

#pragma unroll
  for (int n = 0; n < 4; ++n) {
    const int ccol = n0 + wc * 64 + n * 16 + lr;
    const float bb = bias[ccol];
#pragma unroll
    for (int m = 0; m < 4; ++m) {
      const int crow0 = m0 + wr * 64 + m * 16 + lg * 4;
#pragma unroll
      for (int j = 0; j < 4; ++j)
        C[(size_t)(crow0 + j) * DM + ccol] = f2bf(acc[m][n][j] + bb);
    }
  }
}

// ---------------- V transpose: [4096,1024] -> [1024,4096] ----------------
__global__ void transpose_bf(const unsigned short* __restrict__ src, unsigned short* __restrict__ dst) {
  __shared__ unsigned short tb[32][33];
  const int x = threadIdx.x & 31, y = threadIdx.x >> 5;
  const int bx = blockIdx.x, by = blockIdx.y;
#pragma unroll
  for (int r = 0; r < 32; r += 8)
    tb[r + y][x] = src[(size_t)(by * 32 + r + y) * DM + bx * 32 + x];
  __syncthreads();
#pragma unroll
  for (int r = 0; r < 32; r += 8)
    dst[(size_t)(bx * 32 + r + y) * 4096 + by * 32 + x] = tb[x][r + y];
}

// ---------------- fused attention v5: XCD supertiling + nontemporal attn stores ----------------
// XCD c = bx&7 owns 4 (b,h) pairs (bh = c*4+j); within XCD, j fastest, qt outer:
// K/V of the 4 pairs (4 MB) stays resident in that XCD's L2 for the whole sequence;
// mask tile read by 4 adjacent blocks (L2) and concurrently on the b-matched XCDs (L3).
// attn writes use nontemporal stores to keep the 537 MB stream out of L2.
__global__ __launch_bounds__(512, 4) void attn5_kernel(
    const unsigned short* __restrict__ Qp, const unsigned short* __restrict__ Kp,
    const unsigned short* __restrict__ Vt, const int* __restrict__ mask,
    float* __restrict__ outp, float* __restrict__ attnp) {
  __shared__ float rsred[8][16];
  __shared__ float outred[8][16 * 64];               // 32 KB
  __shared__ unsigned short Pb[8][2][16 * 40];       // 20 KB, double-buffered repack

  const int bx = blockIdx.x;
  const int c  = bx & 7;            // XCD (round-robin dispatch)
  const int s  = bx >> 3;           // temporal order within XCD
  const int j  = s & 3;             // which of this XCD's 4 (b,h) pairs
  const int qt = s >> 2;            // 0..127, outer
  const int bh = c * 4 + j;
  const int b  = bh >> 4, h = bh & 15;
  const int q0 = qt << 4;

  const int w = threadIdx.x >> 6, l = threadIdx.x & 63;
  const int lr = l & 15, lg = l >> 4;
  const int kw0 = w << 8;                      // 256 keys per wave

  const float scale = 0.125f;
  const f32x4 fz = {0.f, 0.f, 0.f, 0.f};

  // Q as B-operand: lane holds Q[q0+lr][lg*8..+7]
  const unsigned short* Qh = Qp + (size_t)(b * S_LEN + q0 + lr) * DM + h * 64;
  const bf16x8 qf0 = *(const bf16x8*)(Qh + lg * 8);
  const bf16x8 qf1 = *(const bf16x8*)(Qh + 32 + lg * 8);

  const unsigned short* Kh = Kp + (size_t)b * S_LEN * DM + h * 64 + (size_t)kw0 * DM;
  const int* mrow = mask + (size_t)(b * S_LEN + q0 + lr) * S_LEN + kw0;

  // ---- QK^T + mask + exp (one pass over K), packed bf16 in regs ----
  unsigned int pkA[16], pkB[16];
  float rs = 0.f;
#pragma unroll
  for (int i = 0; i < 16; ++i) {
    const unsigned short* Kr = Kh + (size_t)(i * 16 + lr) * DM;
    const bf16x8 ka0 = *(const bf16x8*)(Kr + lg * 8);
    const bf16x8 ka1 = *(const bf16x8*)(Kr + 32 + lg * 8);
    const i32x4 m4 = *(const i32x4*)(mrow + i * 16 + lg * 4);
    f32x4 sc = fz;
    sc = __builtin_amdgcn_mfma_f32_16x16x32_bf16(ka0, qf0, sc, 0, 0, 0);
    sc = __builtin_amdgcn_mfma_f32_16x16x32_bf16(ka1, qf1, sc, 0, 0, 0);
    const float e0 = __expf((m4[0] == 0) ? NEGV : sc[0] * scale);
    const float e1 = __expf((m4[1] == 0) ? NEGV : sc[1] * scale);
    const float e2 = __expf((m4[2] == 0) ? NEGV : sc[2] * scale);
    const float e3 = __expf((m4[3] == 0) ? NEGV : sc[3] * scale);
    rs += (e0 + e1) + (e2 + e3);
    pkA[i] = pack_bf2(e0, e1);
    pkB[i] = pack_bf2(e2, e3);
  }
  // per-wave row sum for q=lr (4 lanes with same lr hold partials)
  rs += __shfl_xor(rs, 16, 64);
  rs += __shfl_xor(rs, 32, 64);
  if (l < 16) rsred[w][l] = rs;
  __syncthreads();
  float ssum = 0.f;
#pragma unroll
  for (int ww = 0; ww < 8; ++ww) ssum += rsred[ww][lr];
  const float rinv = 1.0f / ssum;

  // ---- normalize + attn store + PV ----
  float* attnq = attnp + (size_t)((b * 16 + h) * S_LEN + q0 + lr) * S_LEN + kw0;
  const unsigned short* Vh = Vt + (size_t)(h * 64) * (2 * S_LEN) + (size_t)b * S_LEN + kw0;

  f32x4 oacc[4];
#pragma unroll
  for (int n = 0; n < 4; ++n) oacc[n] = fz;

#pragma unroll
  for (int win = 0; win < 8; ++win) {
    const int wb = win * 32;
    const unsigned int a0 = pkA[2 * win],     a1 = pkB[2 * win];
    const unsigned int b0 = pkA[2 * win + 1], b1 = pkB[2 * win + 1];
    float p0 = __uint_as_float(a0 << 16) * rinv;
    float p1 = __uint_as_float(a0 & 0xffff0000u) * rinv;
    float p2 = __uint_as_float(a1 << 16) * rinv;
    float p3 = __uint_as_float(a1 & 0xffff0000u) * rinv;
    float p4 = __uint_as_float(b0 << 16) * rinv;
    float p5 = __uint_as_float(b0 & 0xffff0000u) * rinv;
    float p6 = __uint_as_float(b1 << 16) * rinv;
    float p7 = __uint_as_float(b1 & 0xffff0000u) * rinv;
    const f32x4 st0 = {p0, p1, p2, p3};
    const f32x4 st1 = {p4, p5, p6, p7};
    // nontemporal: keep the 537 MB attn stream out of L2 (protect K/V residency)
    __builtin_nontemporal_store(st0, (f32x4*)(attnq + wb + lg * 4));
    __builtin_nontemporal_store(st1, (f32x4*)(attnq + wb + 16 + lg * 4));

    us4 w0, w1;
    w0[0] = f2bf(p0); w0[1] = f2bf(p1); w0[2] = f2bf(p2); w0[3] = f2bf(p3);
    w1[0] = f2bf(p4); w1[1] = f2bf(p5); w1[2] = f2bf(p6); w1[3] = f2bf(p7);
    unsigned short* pb = &Pb[w][win & 1][0];
    *(us4*)(pb + lr * 40 + lg * 4) = w0;
    *(us4*)(pb + lr * 40 + 16 + lg * 4) = w1;
    const bf16x8 pa = *(const bf16x8*)(pb + lr * 40 + lg * 8);  // A[q=lr][k=lg*8..+7]

#pragma unroll
    for (int n = 0; n < 4; ++n) {
      const bf16x8 vb = *(const bf16x8*)(Vh + (size_t)(n * 16 + lr) * (2 * S_LEN) + wb + lg * 8);
      oacc[n] = __builtin_amdgcn_mfma_f32_16x16x32_bf16(pa, vb, oacc[n], 0, 0, 0);
    }
  }

  // ---- cross-wave out reduction (8 partials) ----
#pragma unroll
  for (int n = 0; n < 4; ++n)
#pragma unroll
    for (int jj = 0; jj < 4; ++jj)
      outred[w][(lg * 4 + jj) * 64 + n * 16 + lr] = oacc[n][jj];
  __syncthreads();
  if (threadIdx.x < 256) {
    const int q = threadIdx.x >> 4;
    const int d0 = (threadIdx.x & 15) * 4;
    float4 o = {0.f, 0.f, 0.f, 0.f};
#pragma unroll
    for (int ww = 0; ww < 8; ++ww) {
      const f32x4 sv = *(const f32x4*)&outred[ww][q * 64 + d0];
      o.x += sv[0]; o.y += sv[1]; o.z += sv[2]; o.w += sv[3];
    }
    *(float4*)(outp + (size_t)(b * S_LEN + q0 + q) * DM + h * 64 + d0) = o;
  }
}

extern "C" void kernel_launch(void* const* d_in, const int* in_sizes, int n_in,
                              void* d_out, int out_size, void* d_ws, size_t ws_size,
                              hipStream_t stream) {
  const float* query = (const float*)d_in[0];
  const float* key_  = (const float*)d_in[1];
  const float* value = (const float*)d_in[2];
  const int*   mask  = (const int*)d_in[3];
  const float* Wq = (const float*)d_in[4];
  const float* bq = (const float*)d_in[5];
  const float* Wk = (const float*)d_in[6];
  const float* bk = (const float*)d_in[7];
  const float* Wv = (const float*)d_in[8];
  const float* bv = (const float*)d_in[9];

  float* outp  = (float*)d_out;
  float* attnp = outp + (size_t)2 * S_LEN * DM;

  unsigned short* ws  = (unsigned short*)d_ws;
  unsigned short* qbf = ws;
  unsigned short* kbf = qbf + 4194304;
  unsigned short* vbf = kbf + 4194304;
  unsigned short* wqb = vbf + 4194304;
  unsigned short* wkb = wqb + 1048576;
  unsigned short* wvb = wkb + 1048576;
  unsigned short* qp  = wvb + 1048576;
  unsigned short* kp  = qp + 4194304;
  unsigned short* vp  = kp + 4194304;
  unsigned short* vt  = vp + 4194304;

  cvt_kernel<<<4096, 256, 0, stream>>>(query, qbf, 1048576);
  cvt_kernel<<<4096, 256, 0, stream>>>(key_,  kbf, 1048576);
  cvt_kernel<<<4096, 256, 0, stream>>>(value, vbf, 1048576);
  cvt_kernel<<<1024, 256, 0, stream>>>(Wq, wqb, 262144);
  cvt_kernel<<<1024, 256, 0, stream>>>(Wk, wkb, 262144);
  cvt_kernel<<<1024, 256, 0, stream>>>(Wv, wvb, 262144);

  proj_gemm<<<dim3(8, 32, 3), 256, 0, stream>>>(qbf, wqb, bq, qp,
                                                kbf, wkb, bk, kp,
                                                vbf, wvb, bv, vp);
  transpose_bf<<<dim3(32, 128), 256, 0, stream>>>(vp, vt);
  attn5_kernel<<<4096, 512, 0, stream>>>(qp, kp, vt, mask, outp, attnp);
}